// Round 2
// baseline (730.476 us; speedup 1.0000x reference)
//
#include <hip/hip_runtime.h>

// B=4, T=1024, C=512, H=8, HD=64, NE=8, K(topk)=2, FF=2048
// All heavy matmuls in bf16 MFMA (16x16x32), fp32 accumulate.
// Router scores computed in pure fp32 (fused LN2+score) to match reference
// top-2 selection: bf16-based scores flipped near-tied experts (absmax 0.14).

typedef unsigned short u16;
typedef __attribute__((ext_vector_type(8))) short s16x8;
typedef __attribute__((ext_vector_type(4))) float f32x4;

__device__ __forceinline__ u16 f2bf(float f) {
  union { float f; unsigned u; } v; v.f = f;
  unsigned r = v.u + 0x7fffu + ((v.u >> 16) & 1u);  // RNE
  return (u16)(r >> 16);
}
__device__ __forceinline__ float bf2f(u16 h) {
  union { unsigned u; float f; } v; v.u = ((unsigned)h) << 16;
  return v.f;
}

#define GLDS16(g, s) __builtin_amdgcn_global_load_lds( \
    (const __attribute__((address_space(1))) void*)(g), \
    (__attribute__((address_space(3))) void*)(s), 16, 0, 0)

#define MFMA16(a, b, c) __builtin_amdgcn_mfma_f32_16x16x32_bf16((a), (b), (c), 0, 0, 0)

// -------- transpose + fp32->bf16 convert: in [R][C] fp32 -> out [C][R] bf16 ----
__global__ __launch_bounds__(256) void transpose_k(
    const float* __restrict__ in, u16* __restrict__ out,
    int R, int C, long long ibs, long long obs, float scale)
{
  __shared__ float tile[32][33];
  in  += (long long)blockIdx.z * ibs;
  out += (long long)blockIdx.z * obs;
  const int c0 = blockIdx.x * 32, r0 = blockIdx.y * 32;
  const int tx = threadIdx.x, ty = threadIdx.y;  // (32,8)
  #pragma unroll
  for (int i = 0; i < 4; ++i)
    tile[ty + i*8][tx] = in[(size_t)(r0 + ty + i*8) * C + c0 + tx];
  __syncthreads();
  #pragma unroll
  for (int i = 0; i < 4; ++i)
    out[(size_t)(c0 + ty + i*8) * R + r0 + tx] = f2bf(tile[tx][ty + i*8] * scale);
}

// -------- LayerNorm (C=512): fp32 in -> bf16 out -----------------------------
__global__ __launch_bounds__(256) void ln_k(
    const float* __restrict__ x, const float* __restrict__ g,
    const float* __restrict__ b, u16* __restrict__ o)
{
  const int row = blockIdx.x, t = threadIdx.x;
  const float* xr = x + (size_t)row * 512;
  const float a0 = xr[t], a1 = xr[t + 256];
  float s = a0 + a1, ss = a0*a0 + a1*a1;
  #pragma unroll
  for (int off = 1; off < 64; off <<= 1) {
    s  += __shfl_xor(s, off);
    ss += __shfl_xor(ss, off);
  }
  __shared__ float rs[4], rq[4];
  const int w = t >> 6;
  if ((t & 63) == 0) { rs[w] = s; rq[w] = ss; }
  __syncthreads();
  s  = rs[0] + rs[1] + rs[2] + rs[3];
  ss = rq[0] + rq[1] + rq[2] + rq[3];
  const float mu = s * (1.f/512.f);
  const float var = ss * (1.f/512.f) - mu*mu;   // biased, matches jnp.var
  const float rstd = rsqrtf(var + 1e-5f);
  o[(size_t)row*512 + t]       = f2bf((a0 - mu) * rstd * g[t]     + b[t]);
  o[(size_t)row*512 + t + 256] = f2bf((a1 - mu) * rstd * g[t+256] + b[t+256]);
}

// -------- m97-structure GEMM: A[M][K] bf16  x  Bt[N][K] bf16 -> epilogues ----
// BM=BN=128, BK=32, 4 waves (2x2), wave tile 64x64 (4x4 fragments of 16x16).
// EPI 0: obf = acc (bf16)
// EPI 1: obf = relu(acc + bias[col]) (bf16)
// EPI 2: oa  = acc + bias[col] + extra[row*N+col]  (fp32; residual add)
// EPI 3: oa += extra[row*8] * (acc + bias[col])    (fp32; router-gated accum)
template<int EPI>
__global__ __launch_bounds__(256) void gemm_bt(
    const u16* __restrict__ A, const u16* __restrict__ Bt,
    int M, int N, int K,
    u16* __restrict__ obf, float* __restrict__ oa,
    const float* __restrict__ bias, const float* __restrict__ extra)
{
  __shared__ u16 Asm[128*32];
  __shared__ u16 Bsm[128*32];
  const int t = threadIdx.x;
  const int l = t & 63;
  const int wid = t >> 6, wr = wid >> 1, wc = wid & 1;
  const int lrow = l & 15, lhi = l >> 4;
  const int m0 = blockIdx.x * 128, n0 = blockIdx.y * 128;

  const f32x4 z4 = {0.f, 0.f, 0.f, 0.f};
  f32x4 acc[4][4];
  #pragma unroll
  for (int i = 0; i < 4; ++i)
    #pragma unroll
    for (int j = 0; j < 4; ++j) acc[i][j] = z4;

  // staging: thread t covers row t>>2 (+64 on 2nd issue), cols (t&3)*8..+7
  // LDS linear row-major [128][32] bf16 -> byte offset t*16 (wave-uniform-base+lane*16)
  const u16* ga = A  + (size_t)(m0 + (t >> 2)) * K + (t & 3) * 8;
  const u16* gb = Bt + (size_t)(n0 + (t >> 2)) * K + (t & 3) * 8;
  const int aoff = (wr*64 + lrow)*32 + lhi*8;
  const int boff = (wc*64 + lrow)*32 + lhi*8;

  for (int k0 = 0; k0 < K; k0 += 32) {
    GLDS16(ga + k0,                (char*)Asm + t*16);
    GLDS16(ga + (size_t)64*K + k0, (char*)Asm + 4096 + t*16);
    GLDS16(gb + k0,                (char*)Bsm + t*16);
    GLDS16(gb + (size_t)64*K + k0, (char*)Bsm + 4096 + t*16);
    __syncthreads();
    s16x8 af[4], bfr[4];
    #pragma unroll
    for (int i = 0; i < 4; ++i) af[i]  = *(const s16x8*)(Asm + aoff + i*16*32);
    #pragma unroll
    for (int j = 0; j < 4; ++j) bfr[j] = *(const s16x8*)(Bsm + boff + j*16*32);
    #pragma unroll
    for (int i = 0; i < 4; ++i)
      #pragma unroll
      for (int j = 0; j < 4; ++j)
        acc[i][j] = MFMA16(af[i], bfr[j], acc[i][j]);
    __syncthreads();
  }

  // C/D layout (m89-verified): col = lane&15, row = (lane>>4)*4 + reg
  #pragma unroll
  for (int i = 0; i < 4; ++i) {
    const int rbase = m0 + wr*64 + i*16 + lhi*4;
    #pragma unroll
    for (int j = 0; j < 4; ++j) {
      const int col = n0 + wc*64 + j*16 + lrow;
      #pragma unroll
      for (int rr = 0; rr < 4; ++rr) {
        const int row = rbase + rr;
        const float v = acc[i][j][rr];
        if (EPI == 0) {
          obf[(size_t)row*N + col] = f2bf(v);
        } else if (EPI == 1) {
          obf[(size_t)row*N + col] = f2bf(fmaxf(v + bias[col], 0.f));
        } else if (EPI == 2) {
          oa[(size_t)row*N + col] = v + bias[col] + extra[(size_t)row*N + col];
        } else {
          oa[(size_t)row*N + col] += extra[(size_t)row*8] * (v + bias[col]);
        }
      }
    }
  }
}

// -------- flash attention: qkv [B*T][1536] bf16 (q|k|v, q pre-scaled 1/8) ----
// grid (T/64, B*H), 256 thr. Wave w owns 16 q-rows; KB=32; online softmax.
__global__ __launch_bounds__(256) void attn_k(
    const u16* __restrict__ qkv, u16* __restrict__ o)
{
  const int l = threadIdx.x & 63, w = threadIdx.x >> 6;
  const int lrow = l & 15, lhi = l >> 4;
  const int qb = blockIdx.x, bh = blockIdx.y;
  const int b = bh >> 3, h = bh & 7;
  const u16* base = qkv + (size_t)b * 1024 * 1536 + h * 64;
  const int t0 = qb*64 + w*16;

  s16x8 qf[2];
  {
    const u16* qrow = base + (size_t)(t0 + lrow) * 1536 + lhi*8;
    qf[0] = *(const s16x8*)qrow;
    qf[1] = *(const s16x8*)(qrow + 32);
  }
  const f32x4 z4 = {0.f,0.f,0.f,0.f};
  float m[4], sl[4];
  f32x4 oacc[4];
  #pragma unroll
  for (int rr = 0; rr < 4; ++rr) { m[rr] = -1e30f; sl[rr] = 0.f; }
  #pragma unroll
  for (int ct = 0; ct < 4; ++ct) oacc[ct] = z4;

  __shared__ u16 P[4][2][16][40];  // per-wave, double-buffered, row pad 40 (2-way max)

  const int nkv = (t0 + 47) >> 5;  // ceil((t0+16)/32)
  for (int kv = 0; kv < nkv; ++kv) {
    const int s0 = kv * 32;
    f32x4 sacc[2] = {z4, z4};
    #pragma unroll
    for (int nt = 0; nt < 2; ++nt) {
      const u16* krow = base + 512 + (size_t)(s0 + nt*16 + lrow) * 1536 + lhi*8;
      s16x8 kf0 = *(const s16x8*)krow;
      s16x8 kf1 = *(const s16x8*)(krow + 32);
      sacc[nt] = MFMA16(qf[0], kf0, sacc[nt]);
      sacc[nt] = MFMA16(qf[1], kf1, sacc[nt]);
    }
    if (s0 + 31 > t0) {  // causal mask s > t
      #pragma unroll
      for (int nt = 0; nt < 2; ++nt)
        #pragma unroll
        for (int rr = 0; rr < 4; ++rr)
          if (s0 + nt*16 + lrow > t0 + lhi*4 + rr) sacc[nt][rr] = -1e30f;
    }
    float pm[4];
    #pragma unroll
    for (int rr = 0; rr < 4; ++rr) pm[rr] = fmaxf(sacc[0][rr], sacc[1][rr]);
    #pragma unroll
    for (int rr = 0; rr < 4; ++rr) {
      pm[rr] = fmaxf(pm[rr], __shfl_xor(pm[rr], 1));
      pm[rr] = fmaxf(pm[rr], __shfl_xor(pm[rr], 2));
      pm[rr] = fmaxf(pm[rr], __shfl_xor(pm[rr], 4));
      pm[rr] = fmaxf(pm[rr], __shfl_xor(pm[rr], 8));
    }
    float p0[4], p1[4], ps[4], scv[4];
    #pragma unroll
    for (int rr = 0; rr < 4; ++rr) {
      const float mn = fmaxf(m[rr], pm[rr]);
      scv[rr] = __expf(m[rr] - mn);
      m[rr] = mn;
      p0[rr] = __expf(sacc[0][rr] - mn);
      p1[rr] = __expf(sacc[1][rr] - mn);
      ps[rr] = p0[rr] + p1[rr];
    }
    #pragma unroll
    for (int rr = 0; rr < 4; ++rr) {
      ps[rr] += __shfl_xor(ps[rr], 1);
      ps[rr] += __shfl_xor(ps[rr], 2);
      ps[rr] += __shfl_xor(ps[rr], 4);
      ps[rr] += __shfl_xor(ps[rr], 8);
      sl[rr] = sl[rr] * scv[rr] + ps[rr];
    }
    #pragma unroll
    for (int ct = 0; ct < 4; ++ct) {
      f32x4 t4 = oacc[ct];
      #pragma unroll
      for (int rr = 0; rr < 4; ++rr) t4[rr] *= scv[rr];
      oacc[ct] = t4;
    }
    const int buf = kv & 1;
    #pragma unroll
    for (int rr = 0; rr < 4; ++rr) {
      P[w][buf][lhi*4 + rr][lrow]      = f2bf(p0[rr]);
      P[w][buf][lhi*4 + rr][16 + lrow] = f2bf(p1[rr]);
    }
    asm volatile("s_waitcnt lgkmcnt(0)" ::: "memory");
    __builtin_amdgcn_sched_barrier(0);
    s16x8 pa = *(const s16x8*)&P[w][buf][lrow][lhi*8];
    #pragma unroll
    for (int ct = 0; ct < 4; ++ct) {
      const u16* vp = base + 1024 + (size_t)(s0 + lhi*8) * 1536 + ct*16 + lrow;
      s16x8 vf;
      #pragma unroll
      for (int j = 0; j < 8; ++j) vf[j] = (short)vp[(size_t)j * 1536];
      oacc[ct] = MFMA16(pa, vf, oacc[ct]);
    }
    asm volatile("" ::: "memory");
  }
  #pragma unroll
  for (int ct = 0; ct < 4; ++ct)
    #pragma unroll
    for (int rr = 0; rr < 4; ++rr) {
      const int row = b*1024 + t0 + lhi*4 + rr;
      o[(size_t)row*512 + h*64 + ct*16 + lrow] = f2bf(oacc[ct][rr] / sl[rr]);
    }
}

// -------- fused LN2 + router, all fp32 (top-2 selection must match reference)
// one wave per token; lane l owns 8 contiguous channels [l*8, l*8+8)
__global__ __launch_bounds__(256) void router_k(
    const float* __restrict__ x2, const float* __restrict__ g,
    const float* __restrict__ b, const float* __restrict__ Wr,
    const float* __restrict__ br, float* __restrict__ rt)
{
  const int l = threadIdx.x & 63, w = threadIdx.x >> 6;
  const int tkn = blockIdx.x * 4 + w;
  const float* xr = x2 + (size_t)tkn * 512;
  float v[8];
  float s = 0.f, ss = 0.f;
  #pragma unroll
  for (int i = 0; i < 8; ++i) {
    v[i] = xr[l*8 + i];
    s += v[i]; ss += v[i]*v[i];
  }
  #pragma unroll
  for (int off = 1; off < 64; off <<= 1) {
    s  += __shfl_xor(s, off);
    ss += __shfl_xor(ss, off);
  }
  const float mu = s * (1.f/512.f);
  const float var = ss * (1.f/512.f) - mu*mu;
  const float rstd = rsqrtf(var + 1e-5f);
  float acc[8];
  #pragma unroll
  for (int e = 0; e < 8; ++e) acc[e] = 0.f;
  #pragma unroll
  for (int i = 0; i < 8; ++i) {
    const int c = l*8 + i;
    const float hv = (v[i] - mu) * rstd * g[c] + b[c];
    const float* wrow = Wr + (size_t)c * 8;
    #pragma unroll
    for (int e = 0; e < 8; ++e) acc[e] += hv * wrow[e];
  }
  #pragma unroll
  for (int e = 0; e < 8; ++e) {
    #pragma unroll
    for (int off = 1; off < 64; off <<= 1) acc[e] += __shfl_xor(acc[e], off);
    acc[e] += br[e];
  }
  int e1 = 0;
  #pragma unroll
  for (int e = 1; e < 8; ++e) if (acc[e] > acc[e1]) e1 = e;
  int e2 = (e1 == 0) ? 1 : 0;
  #pragma unroll
  for (int e = 0; e < 8; ++e) if (e != e1 && acc[e] > acc[e2]) e2 = e;
  const float mx = fmaxf(acc[e1], 0.f);  // mask = {scores at top2, 0 elsewhere}
  float Z = 0.f;
  #pragma unroll
  for (int e = 0; e < 8; ++e) {
    const float mv = (e == e1 || e == e2) ? acc[e] : 0.f;
    Z += __expf(mv - mx);
  }
  if (l < 8) {
    const float mv = (l == e1 || l == e2) ? acc[l] : 0.f;
    rt[(size_t)tkn * 8 + l] = __expf(mv - mx) / Z;
  }
}

extern "C" void kernel_launch(void* const* d_in, const int* in_sizes, int n_in,
                              void* d_out, int out_size, void* d_ws, size_t ws_size,
                              hipStream_t stream) {
  const float* x    = (const float*)d_in[0];
  const float* ln1g = (const float*)d_in[1];
  const float* ln1b = (const float*)d_in[2];
  const float* ln2g = (const float*)d_in[3];
  const float* ln2b = (const float*)d_in[4];
  const float* Wq   = (const float*)d_in[5];
  const float* Wk   = (const float*)d_in[6];
  const float* Wv   = (const float*)d_in[7];
  const float* Wp   = (const float*)d_in[8];
  const float* bp   = (const float*)d_in[9];
  const float* Wr   = (const float*)d_in[10];
  const float* br   = (const float*)d_in[11];
  const float* W1   = (const float*)d_in[12];
  const float* b1   = (const float*)d_in[13];
  const float* W2   = (const float*)d_in[14];
  const float* b2   = (const float*)d_in[15];
  float* out = (float*)d_out;

  char* ws = (char*)d_ws;
  size_t off = 0;
  auto alloc = [&](size_t bytes) -> char* {
    char* p = ws + off;
    off += (bytes + 255) & ~(size_t)255;
    return p;
  };
  u16* wqkv_t = (u16*)alloc((size_t)1536*512*2);   // [1536][512], rows: q(0-511,h*64+d)|k|v
  u16* wp_t   = (u16*)alloc((size_t)512*512*2);    // [c][hd]
  u16* w1_t   = (u16*)alloc((size_t)8*2048*512*2); // per e: [f][c]
  u16* w2_t   = (u16*)alloc((size_t)8*512*2048*2); // per e: [c][f]
  u16* hb     = (u16*)alloc((size_t)4096*512*2);
  u16* qkvb   = (u16*)alloc((size_t)4096*1536*2);
  u16* attnb  = (u16*)alloc((size_t)4096*512*2);
  u16* h2b    = (u16*)alloc((size_t)4096*512*2);
  float* rout = (float*)alloc((size_t)4096*8*4);
  u16* hidb   = (u16*)alloc((size_t)4096*2048*2);

  const dim3 tb(32, 8);
  // weight prep: transpose to Bt ([N][K]) bf16; fold 1/sqrt(HD)=0.125 into Wq
  transpose_k<<<dim3(2,16,8),  tb, 0, stream>>>(Wq, wqkv_t,              512,   64, 512*64,  (long long)64*512, 0.125f);
  transpose_k<<<dim3(2,16,8),  tb, 0, stream>>>(Wk, wqkv_t + 512*512,    512,   64, 512*64,  (long long)64*512, 1.f);
  transpose_k<<<dim3(2,16,8),  tb, 0, stream>>>(Wv, wqkv_t + 2*512*512,  512,   64, 512*64,  (long long)64*512, 1.f);
  transpose_k<<<dim3(16,16,1), tb, 0, stream>>>(Wp, wp_t,                512,  512, 0, 0, 1.f);
  transpose_k<<<dim3(64,16,8), tb, 0, stream>>>(W1, w1_t,                512, 2048, (long long)512*2048, (long long)2048*512, 1.f);
  transpose_k<<<dim3(16,64,8), tb, 0, stream>>>(W2, w2_t,               2048,  512, (long long)2048*512, (long long)512*2048, 1.f);

  // LN1 -> hb
  ln_k<<<4096, 256, 0, stream>>>(x, ln1g, ln1b, hb);
  // fused QKV: [4096,512] x [1536,512]^T -> qkvb [4096][1536]
  gemm_bt<0><<<dim3(32,12), 256, 0, stream>>>(hb, wqkv_t, 4096, 1536, 512, qkvb, nullptr, nullptr, nullptr);
  // attention -> attnb [4096][512] (h-major cols)
  attn_k<<<dim3(16,32), 256, 0, stream>>>(qkvb, attnb);
  // proj + residual: out = x + attn@Wp + bp
  gemm_bt<2><<<dim3(32,4), 256, 0, stream>>>(attnb, wp_t, 4096, 512, 512, nullptr, out, bp, x);
  // LN2 (bf16, feeds expert GEMMs) -> h2b
  ln_k<<<4096, 256, 0, stream>>>(out, ln2g, ln2b, h2b);
  // fused fp32 LN2+router (exact top-2 semantics) from x2 = out
  router_k<<<1024, 256, 0, stream>>>(out, ln2g, ln2b, Wr, br, rout);
  // dense MoE: all 8 experts, gated accumulate into out
  for (int e = 0; e < 8; ++e) {
    gemm_bt<1><<<dim3(32,16), 256, 0, stream>>>(h2b, w1_t + (size_t)e*2048*512, 4096, 2048, 512,
                                                hidb, nullptr, b1 + (size_t)e*2048, nullptr);
    gemm_bt<3><<<dim3(32,4), 256, 0, stream>>>(hidb, w2_t + (size_t)e*512*2048, 4096, 512, 2048,
                                               nullptr, out, b2 + (size_t)e*512, rout + e);
  }
}

// Round 3
// 429.869 us; speedup vs baseline: 1.6993x; 1.6993x over previous
//
#include <hip/hip_runtime.h>

// B=4, T=1024, C=512, H=8, HD=64, NE=8, K(topk)=2, FF=2048
// bf16 MFMA (16x16x32), fp32 accumulate. Round-2 restructure:
//  - GEMM1 merged over expert PAIRS (N=4096, 1024 blocks) with relu+b1+router
//    gate fused into epilogue (hid pre-scaled by r_e).
//  - GEMM2 split-K z=2 (one z per expert of the pair), BN=64 -> 512 blocks,
//    accumulating into 2 bf16 partial planes across the 4 sequential pairs.
//  - combine kernel: out += P0 + P1 + sum_e r_e*b2_e.
//  - BK=64 (halved barrier count vs BK=32).

typedef unsigned short u16;
typedef __attribute__((ext_vector_type(8))) short s16x8;
typedef __attribute__((ext_vector_type(4))) float f32x4;

__device__ __forceinline__ u16 f2bf(float f) {
  union { float f; unsigned u; } v; v.f = f;
  unsigned r = v.u + 0x7fffu + ((v.u >> 16) & 1u);  // RNE
  return (u16)(r >> 16);
}
__device__ __forceinline__ float bf2f(u16 h) {
  union { unsigned u; float f; } v; v.u = ((unsigned)h) << 16;
  return v.f;
}

#define GLDS16(g, s) __builtin_amdgcn_global_load_lds( \
    (const __attribute__((address_space(1))) void*)(g), \
    (__attribute__((address_space(3))) void*)(s), 16, 0, 0)

#define MFMA16(a, b, c) __builtin_amdgcn_mfma_f32_16x16x32_bf16((a), (b), (c), 0, 0, 0)

// -------- transpose + fp32->bf16 convert: in [R][C] fp32 -> out [C][R] bf16 ----
__global__ __launch_bounds__(256) void transpose_k(
    const float* __restrict__ in, u16* __restrict__ out,
    int R, int C, long long ibs, long long obs, float scale)
{
  __shared__ float tile[32][33];
  in  += (long long)blockIdx.z * ibs;
  out += (long long)blockIdx.z * obs;
  const int c0 = blockIdx.x * 32, r0 = blockIdx.y * 32;
  const int tx = threadIdx.x, ty = threadIdx.y;  // (32,8)
  #pragma unroll
  for (int i = 0; i < 4; ++i)
    tile[ty + i*8][tx] = in[(size_t)(r0 + ty + i*8) * C + c0 + tx];
  __syncthreads();
  #pragma unroll
  for (int i = 0; i < 4; ++i)
    out[(size_t)(c0 + ty + i*8) * R + r0 + tx] = f2bf(tile[tx][ty + i*8] * scale);
}

// -------- LayerNorm (C=512): fp32 in -> bf16 out -----------------------------
__global__ __launch_bounds__(256) void ln_k(
    const float* __restrict__ x, const float* __restrict__ g,
    const float* __restrict__ b, u16* __restrict__ o)
{
  const int row = blockIdx.x, t = threadIdx.x;
  const float* xr = x + (size_t)row * 512;
  const float a0 = xr[t], a1 = xr[t + 256];
  float s = a0 + a1, ss = a0*a0 + a1*a1;
  #pragma unroll
  for (int off = 1; off < 64; off <<= 1) {
    s  += __shfl_xor(s, off);
    ss += __shfl_xor(ss, off);
  }
  __shared__ float rs[4], rq[4];
  const int w = t >> 6;
  if ((t & 63) == 0) { rs[w] = s; rq[w] = ss; }
  __syncthreads();
  s  = rs[0] + rs[1] + rs[2] + rs[3];
  ss = rq[0] + rq[1] + rq[2] + rq[3];
  const float mu = s * (1.f/512.f);
  const float var = ss * (1.f/512.f) - mu*mu;   // biased, matches jnp.var
  const float rstd = rsqrtf(var + 1e-5f);
  o[(size_t)row*512 + t]       = f2bf((a0 - mu) * rstd * g[t]     + b[t]);
  o[(size_t)row*512 + t + 256] = f2bf((a1 - mu) * rstd * g[t+256] + b[t+256]);
}

// -------- BK=64 GEMM: A[M][lda] bf16 x Bt[N][ldb] bf16, 128x128 tile ---------
// 4 waves (2x2), wave tile 64x64 (4x4 frags). 2 barriers per 64-K.
// EPI 0: obf = acc (bf16)
// EPI 1: obf = r_e * relu(acc + bias[col]) (bf16), e = e0 + (col>>11), r from extra
// EPI 2: oa  = acc + bias[col] + extra[row*N+col]  (fp32 residual)
template<int EPI>
__global__ __launch_bounds__(256) void gemm64(
    const u16* __restrict__ A, const u16* __restrict__ Bt,
    int M, int N, int K, int lda, int ldb,
    u16* __restrict__ obf, float* __restrict__ oa,
    const float* __restrict__ bias, const float* __restrict__ extra, int e0)
{
  __shared__ u16 Asm[128*64];
  __shared__ u16 Bsm[128*64];
  const int t = threadIdx.x;
  const int l = t & 63;
  const int wid = t >> 6, wr = wid >> 1, wc = wid & 1;
  const int lrow = l & 15, lhi = l >> 4;
  const int m0 = blockIdx.x * 128, n0 = blockIdx.y * 128;

  const f32x4 z4 = {0.f, 0.f, 0.f, 0.f};
  f32x4 acc[4][4];
  #pragma unroll
  for (int i = 0; i < 4; ++i)
    #pragma unroll
    for (int j = 0; j < 4; ++j) acc[i][j] = z4;

  // staging: issue i covers rows [i*32, i*32+32); thread t -> row i*32+(t>>3),
  // 16B chunk (t&7). LDS linear [128][64] bf16: byte = i*4096 + t*16.
  const u16* ga = A  + (size_t)(m0 + (t >> 3)) * lda + (t & 7) * 8;
  const u16* gb = Bt + (size_t)(n0 + (t >> 3)) * ldb + (t & 7) * 8;

  for (int k0 = 0; k0 < K; k0 += 64) {
    #pragma unroll
    for (int i = 0; i < 4; ++i) {
      GLDS16(ga + (size_t)i*32*lda + k0, (char*)Asm + i*4096 + t*16);
      GLDS16(gb + (size_t)i*32*ldb + k0, (char*)Bsm + i*4096 + t*16);
    }
    __syncthreads();
    #pragma unroll
    for (int kh = 0; kh < 2; ++kh) {
      s16x8 af[4], bfr[4];
      #pragma unroll
      for (int i = 0; i < 4; ++i)
        af[i]  = *(const s16x8*)(Asm + (wr*64 + i*16 + lrow)*64 + kh*32 + lhi*8);
      #pragma unroll
      for (int j = 0; j < 4; ++j)
        bfr[j] = *(const s16x8*)(Bsm + (wc*64 + j*16 + lrow)*64 + kh*32 + lhi*8);
      #pragma unroll
      for (int i = 0; i < 4; ++i)
        #pragma unroll
        for (int j = 0; j < 4; ++j)
          acc[i][j] = MFMA16(af[i], bfr[j], acc[i][j]);
    }
    __syncthreads();
  }

  // C/D layout: col = lane&15, row = (lane>>4)*4 + reg
  #pragma unroll
  for (int i = 0; i < 4; ++i) {
    const int rbase = m0 + wr*64 + i*16 + lhi*4;
    #pragma unroll
    for (int j = 0; j < 4; ++j) {
      const int col = n0 + wc*64 + j*16 + lrow;
      #pragma unroll
      for (int rr = 0; rr < 4; ++rr) {
        const int row = rbase + rr;
        const float v = acc[i][j][rr];
        if (EPI == 0) {
          obf[(size_t)row*N + col] = f2bf(v);
        } else if (EPI == 1) {
          const float r = extra[(size_t)row*8 + e0 + (col >> 11)];
          obf[(size_t)row*N + col] = f2bf(fmaxf(v + bias[col], 0.f) * r);
        } else {
          oa[(size_t)row*N + col] = v + bias[col] + extra[(size_t)row*N + col];
        }
      }
    }
  }
}

// -------- GEMM2 split-K: hid[4096][4096] (pair, r-scaled) x W2 -> partials ---
// BM=128, BN=64, BK=64, z = expert-in-pair. P has 2 bf16 planes [4096][512];
// pair 0 writes, pairs 1..3 accumulate (sequential launches, race-free).
__global__ __launch_bounds__(256) void gemm2_k(
    const u16* __restrict__ hid, const u16* __restrict__ w2t,
    u16* __restrict__ P, int e0, int accum)
{
  __shared__ u16 Asm[128*64];
  __shared__ u16 Bsm[64*64];
  const int t = threadIdx.x;
  const int l = t & 63;
  const int wid = t >> 6, wr = wid >> 1, wc = wid & 1;
  const int lrow = l & 15, lhi = l >> 4;
  const int m0 = blockIdx.x * 128, n0 = blockIdx.y * 64, z = blockIdx.z;

  const u16* A  = hid + z * 2048;                       // lda 4096
  const u16* Bt = w2t + (size_t)(e0 + z) * 512 * 2048;  // [512][2048]
  u16* Pz = P + (size_t)z * 4096 * 512;

  const f32x4 z4 = {0.f, 0.f, 0.f, 0.f};
  f32x4 acc[4][2];
  #pragma unroll
  for (int i = 0; i < 4; ++i) { acc[i][0] = z4; acc[i][1] = z4; }

  const u16* ga = A  + (size_t)(m0 + (t >> 3)) * 4096 + (t & 7) * 8;
  const u16* gb = Bt + (size_t)(n0 + (t >> 3)) * 2048 + (t & 7) * 8;

  for (int k0 = 0; k0 < 2048; k0 += 64) {
    #pragma unroll
    for (int i = 0; i < 4; ++i)
      GLDS16(ga + (size_t)i*32*4096 + k0, (char*)Asm + i*4096 + t*16);
    #pragma unroll
    for (int i = 0; i < 2; ++i)
      GLDS16(gb + (size_t)i*32*2048 + k0, (char*)Bsm + i*4096 + t*16);
    __syncthreads();
    #pragma unroll
    for (int kh = 0; kh < 2; ++kh) {
      s16x8 af[4], bfr[2];
      #pragma unroll
      for (int i = 0; i < 4; ++i)
        af[i]  = *(const s16x8*)(Asm + (wr*64 + i*16 + lrow)*64 + kh*32 + lhi*8);
      #pragma unroll
      for (int j = 0; j < 2; ++j)
        bfr[j] = *(const s16x8*)(Bsm + (wc*32 + j*16 + lrow)*64 + kh*32 + lhi*8);
      #pragma unroll
      for (int i = 0; i < 4; ++i)
        #pragma unroll
        for (int j = 0; j < 2; ++j)
          acc[i][j] = MFMA16(af[i], bfr[j], acc[i][j]);
    }
    __syncthreads();
  }

  #pragma unroll
  for (int i = 0; i < 4; ++i) {
    const int rbase = m0 + wr*64 + i*16 + lhi*4;
    #pragma unroll
    for (int j = 0; j < 2; ++j) {
      const int col = n0 + wc*32 + j*16 + lrow;
      #pragma unroll
      for (int rr = 0; rr < 4; ++rr) {
        const size_t idx = (size_t)(rbase + rr) * 512 + col;
        const float old = accum ? bf2f(Pz[idx]) : 0.f;
        Pz[idx] = f2bf(old + acc[i][j][rr]);
      }
    }
  }
}

// -------- combine: out += P0 + P1 + sum_e r_e * b2[e] ------------------------
__global__ __launch_bounds__(256) void combine_k(
    float* __restrict__ out, const u16* __restrict__ P,
    const float* __restrict__ rout, const float* __restrict__ b2)
{
  const int row = blockIdx.x, t = threadIdx.x;
  float r[8];
  #pragma unroll
  for (int e = 0; e < 8; ++e) r[e] = rout[(size_t)row*8 + e];
  #pragma unroll
  for (int cc = 0; cc < 2; ++cc) {
    const int c = t + cc*256;
    const size_t idx = (size_t)row*512 + c;
    float v = out[idx] + bf2f(P[idx]) + bf2f(P[(size_t)4096*512 + idx]);
    #pragma unroll
    for (int e = 0; e < 8; ++e) v += r[e] * b2[(size_t)e*512 + c];
    out[idx] = v;
  }
}

// -------- flash attention: qkv [B*T][1536] bf16 (q|k|v, q pre-scaled 1/8) ----
__global__ __launch_bounds__(256) void attn_k(
    const u16* __restrict__ qkv, u16* __restrict__ o)
{
  const int l = threadIdx.x & 63, w = threadIdx.x >> 6;
  const int lrow = l & 15, lhi = l >> 4;
  const int qb = blockIdx.x, bh = blockIdx.y;
  const int b = bh >> 3, h = bh & 7;
  const u16* base = qkv + (size_t)b * 1024 * 1536 + h * 64;
  const int t0 = qb*64 + w*16;

  s16x8 qf[2];
  {
    const u16* qrow = base + (size_t)(t0 + lrow) * 1536 + lhi*8;
    qf[0] = *(const s16x8*)qrow;
    qf[1] = *(const s16x8*)(qrow + 32);
  }
  const f32x4 z4 = {0.f,0.f,0.f,0.f};
  float m[4], sl[4];
  f32x4 oacc[4];
  #pragma unroll
  for (int rr = 0; rr < 4; ++rr) { m[rr] = -1e30f; sl[rr] = 0.f; }
  #pragma unroll
  for (int ct = 0; ct < 4; ++ct) oacc[ct] = z4;

  __shared__ u16 P[4][2][16][40];

  const int nkv = (t0 + 47) >> 5;
  for (int kv = 0; kv < nkv; ++kv) {
    const int s0 = kv * 32;
    f32x4 sacc[2] = {z4, z4};
    #pragma unroll
    for (int nt = 0; nt < 2; ++nt) {
      const u16* krow = base + 512 + (size_t)(s0 + nt*16 + lrow) * 1536 + lhi*8;
      s16x8 kf0 = *(const s16x8*)krow;
      s16x8 kf1 = *(const s16x8*)(krow + 32);
      sacc[nt] = MFMA16(qf[0], kf0, sacc[nt]);
      sacc[nt] = MFMA16(qf[1], kf1, sacc[nt]);
    }
    if (s0 + 31 > t0) {
      #pragma unroll
      for (int nt = 0; nt < 2; ++nt)
        #pragma unroll
        for (int rr = 0; rr < 4; ++rr)
          if (s0 + nt*16 + lrow > t0 + lhi*4 + rr) sacc[nt][rr] = -1e30f;
    }
    float pm[4];
    #pragma unroll
    for (int rr = 0; rr < 4; ++rr) pm[rr] = fmaxf(sacc[0][rr], sacc[1][rr]);
    #pragma unroll
    for (int rr = 0; rr < 4; ++rr) {
      pm[rr] = fmaxf(pm[rr], __shfl_xor(pm[rr], 1));
      pm[rr] = fmaxf(pm[rr], __shfl_xor(pm[rr], 2));
      pm[rr] = fmaxf(pm[rr], __shfl_xor(pm[rr], 4));
      pm[rr] = fmaxf(pm[rr], __shfl_xor(pm[rr], 8));
    }
    float p0[4], p1[4], ps[4], scv[4];
    #pragma unroll
    for (int rr = 0; rr < 4; ++rr) {
      const float mn = fmaxf(m[rr], pm[rr]);
      scv[rr] = __expf(m[rr] - mn);
      m[rr] = mn;
      p0[rr] = __expf(sacc[0][rr] - mn);
      p1[rr] = __expf(sacc[1][rr] - mn);
      ps[rr] = p0[rr] + p1[rr];
    }
    #pragma unroll
    for (int rr = 0; rr < 4; ++rr) {
      ps[rr] += __shfl_xor(ps[rr], 1);
      ps[rr] += __shfl_xor(ps[rr], 2);
      ps[rr] += __shfl_xor(ps[rr], 4);
      ps[rr] += __shfl_xor(ps[rr], 8);
      sl[rr] = sl[rr] * scv[rr] + ps[rr];
    }
    #pragma unroll
    for (int ct = 0; ct < 4; ++ct) {
      f32x4 t4 = oacc[ct];
      #pragma unroll
      for (int rr = 0; rr < 4; ++rr) t4[rr] *= scv[rr];
      oacc[ct] = t4;
    }
    const int buf = kv & 1;
    #pragma unroll
    for (int rr = 0; rr < 4; ++rr) {
      P[w][buf][lhi*4 + rr][lrow]      = f2bf(p0[rr]);
      P[w][buf][lhi*4 + rr][16 + lrow] = f2bf(p1[rr]);
    }
    asm volatile("s_waitcnt lgkmcnt(0)" ::: "memory");
    __builtin_amdgcn_sched_barrier(0);
    s16x8 pa = *(const s16x8*)&P[w][buf][lrow][lhi*8];
    #pragma unroll
    for (int ct = 0; ct < 4; ++ct) {
      const u16* vp = base + 1024 + (size_t)(s0 + lhi*8) * 1536 + ct*16 + lrow;
      s16x8 vf;
      #pragma unroll
      for (int j = 0; j < 8; ++j) vf[j] = (short)vp[(size_t)j * 1536];
      oacc[ct] = MFMA16(pa, vf, oacc[ct]);
    }
    asm volatile("" ::: "memory");
  }
  #pragma unroll
  for (int ct = 0; ct < 4; ++ct)
    #pragma unroll
    for (int rr = 0; rr < 4; ++rr) {
      const int row = b*1024 + t0 + lhi*4 + rr;
      o[(size_t)row*512 + h*64 + ct*16 + lrow] = f2bf(oacc[ct][rr] / sl[rr]);
    }
}

// -------- fused LN2 + router, all fp32 (exact top-2 semantics) ---------------
__global__ __launch_bounds__(256) void router_k(
    const float* __restrict__ x2, const float* __restrict__ g,
    const float* __restrict__ b, const float* __restrict__ Wr,
    const float* __restrict__ br, float* __restrict__ rt)
{
  const int l = threadIdx.x & 63, w = threadIdx.x >> 6;
  const int tkn = blockIdx.x * 4 + w;
  const float* xr = x2 + (size_t)tkn * 512;
  float v[8];
  float s = 0.f, ss = 0.f;
  #pragma unroll
  for (int i = 0; i < 8; ++i) {
    v[i] = xr[l*8 + i];
    s += v[i]; ss += v[i]*v[i];
  }
  #pragma unroll
  for (int off = 1; off < 64; off <<= 1) {
    s  += __shfl_xor(s, off);
    ss += __shfl_xor(ss, off);
  }
  const float mu = s * (1.f/512.f);
  const float var = ss * (1.f/512.f) - mu*mu;
  const float rstd = rsqrtf(var + 1e-5f);
  float acc[8];
  #pragma unroll
  for (int e = 0; e < 8; ++e) acc[e] = 0.f;
  #pragma unroll
  for (int i = 0; i < 8; ++i) {
    const int c = l*8 + i;
    const float hv = (v[i] - mu) * rstd * g[c] + b[c];
    const float* wrow = Wr + (size_t)c * 8;
    #pragma unroll
    for (int e = 0; e < 8; ++e) acc[e] += hv * wrow[e];
  }
  #pragma unroll
  for (int e = 0; e < 8; ++e) {
    #pragma unroll
    for (int off = 1; off < 64; off <<= 1) acc[e] += __shfl_xor(acc[e], off);
    acc[e] += br[e];
  }
  int e1 = 0;
  #pragma unroll
  for (int e = 1; e < 8; ++e) if (acc[e] > acc[e1]) e1 = e;
  int e2 = (e1 == 0) ? 1 : 0;
  #pragma unroll
  for (int e = 0; e < 8; ++e) if (e != e1 && acc[e] > acc[e2]) e2 = e;
  const float mx = fmaxf(acc[e1], 0.f);
  float Z = 0.f;
  #pragma unroll
  for (int e = 0; e < 8; ++e) {
    const float mv = (e == e1 || e == e2) ? acc[e] : 0.f;
    Z += __expf(mv - mx);
  }
  if (l < 8) {
    const float mv = (l == e1 || l == e2) ? acc[l] : 0.f;
    rt[(size_t)tkn * 8 + l] = __expf(mv - mx) / Z;
  }
}

extern "C" void kernel_launch(void* const* d_in, const int* in_sizes, int n_in,
                              void* d_out, int out_size, void* d_ws, size_t ws_size,
                              hipStream_t stream) {
  const float* x    = (const float*)d_in[0];
  const float* ln1g = (const float*)d_in[1];
  const float* ln1b = (const float*)d_in[2];
  const float* ln2g = (const float*)d_in[3];
  const float* ln2b = (const float*)d_in[4];
  const float* Wq   = (const float*)d_in[5];
  const float* Wk   = (const float*)d_in[6];
  const float* Wv   = (const float*)d_in[7];
  const float* Wp   = (const float*)d_in[8];
  const float* bp   = (const float*)d_in[9];
  const float* Wr   = (const float*)d_in[10];
  const float* br   = (const float*)d_in[11];
  const float* W1   = (const float*)d_in[12];
  const float* b1   = (const float*)d_in[13];
  const float* W2   = (const float*)d_in[14];
  const float* b2   = (const float*)d_in[15];
  float* out = (float*)d_out;

  char* ws = (char*)d_ws;
  size_t off = 0;
  auto alloc = [&](size_t bytes) -> char* {
    char* p = ws + off;
    off += (bytes + 255) & ~(size_t)255;
    return p;
  };
  // persistent through MoE phase:
  u16* w1_t = (u16*)alloc((size_t)8*2048*512*2);   // per e: [f][c]
  u16* w2_t = (u16*)alloc((size_t)8*512*2048*2);   // per e: [c][f]
  u16* h2b  = (u16*)alloc((size_t)4096*512*2);
  float* rout = (float*)alloc((size_t)4096*8*4);
  u16* hidb = (u16*)alloc((size_t)4096*4096*2);    // pair hid (r-scaled), 32 MiB
  u16* Ppl  = (u16*)alloc((size_t)2*4096*512*2);   // 2 bf16 partial planes
  // attention-phase buffers overlay the hidb region (dead before first G1):
  u16* wqkv_t = (u16*)hidb;                          // 1536*512*2  = 1.5 MiB
  u16* wp_t   = (u16*)((char*)hidb + 1572864);       //  512*512*2  = 0.5 MiB
  u16* hb     = (u16*)((char*)hidb + 2097152);       // 4096*512*2  = 4 MiB
  u16* attnb  = (u16*)((char*)hidb + 6291456);       // 4096*512*2  = 4 MiB
  u16* qkvb   = (u16*)((char*)hidb + 10485760);      // 4096*1536*2 = 12 MiB (ends 22 MiB < 32 MiB)

  const dim3 tb(32, 8);
  // weight prep: transpose to Bt ([N][K]) bf16; fold 1/sqrt(HD)=0.125 into Wq
  transpose_k<<<dim3(2,16,8),  tb, 0, stream>>>(Wq, wqkv_t,              512,   64, 512*64,  (long long)64*512, 0.125f);
  transpose_k<<<dim3(2,16,8),  tb, 0, stream>>>(Wk, wqkv_t + 512*512,    512,   64, 512*64,  (long long)64*512, 1.f);
  transpose_k<<<dim3(2,16,8),  tb, 0, stream>>>(Wv, wqkv_t + 2*512*512,  512,   64, 512*64,  (long long)64*512, 1.f);
  transpose_k<<<dim3(16,16,1), tb, 0, stream>>>(Wp, wp_t,                512,  512, 0, 0, 1.f);
  transpose_k<<<dim3(64,16,8), tb, 0, stream>>>(W1, w1_t,                512, 2048, (long long)512*2048, (long long)2048*512, 1.f);
  transpose_k<<<dim3(16,64,8), tb, 0, stream>>>(W2, w2_t,               2048,  512, (long long)2048*512, (long long)512*2048, 1.f);

  // LN1 -> hb
  ln_k<<<4096, 256, 0, stream>>>(x, ln1g, ln1b, hb);
  // fused QKV: [4096,512] x [1536,512]^T -> qkvb
  gemm64<0><<<dim3(32,12), 256, 0, stream>>>(hb, wqkv_t, 4096, 1536, 512, 512, 512,
                                             qkvb, nullptr, nullptr, nullptr, 0);
  // attention -> attnb
  attn_k<<<dim3(16,32), 256, 0, stream>>>(qkvb, attnb);
  // proj + residual: out = x + attn@Wp + bp
  gemm64<2><<<dim3(32,4), 256, 0, stream>>>(attnb, wp_t, 4096, 512, 512, 512, 512,
                                            nullptr, out, bp, x, 0);
  // LN2 (bf16, feeds expert GEMMs) -> h2b
  ln_k<<<4096, 256, 0, stream>>>(out, ln2g, ln2b, h2b);
  // fp32 LN2+router (exact top-2) from x2 = out
  router_k<<<1024, 256, 0, stream>>>(out, ln2g, ln2b, Wr, br, rout);

  // dense MoE in 4 expert-pairs
  for (int p = 0; p < 4; ++p) {
    const int e0 = 2*p;
    // G1 pair: hid[:, 0:4096] = r_e * relu(h2 @ W1_e + b1_e) for e in {e0,e0+1}
    gemm64<1><<<dim3(32,32), 256, 0, stream>>>(h2b, w1_t + (size_t)e0*2048*512,
                                               4096, 4096, 512, 512, 512,
                                               hidb, nullptr, b1 + (size_t)e0*2048, rout, e0);
    // G2 split-K over the pair (z = expert), accumulate bf16 partials
    gemm2_k<<<dim3(32,8,2), 256, 0, stream>>>(hidb, w2_t, Ppl, e0, p > 0 ? 1 : 0);
  }
  // out += P0 + P1 + sum_e r_e * b2_e
  combine_k<<<4096, 256, 0, stream>>>(out, Ppl, rout, b2);
}